// Round 9
// baseline (116.928 us; speedup 1.0000x reference)
//
#include <hip/hip_runtime.h>
#include <hip/hip_bf16.h>
#include <hip/hip_cooperative_groups.h>

namespace cg = cooperative_groups;

#define B_ 4096
#define L_ 50
#define D_ 64

typedef __attribute__((ext_vector_type(8))) short short8;
typedef __attribute__((ext_vector_type(4))) float f32x4;

__device__ __forceinline__ float sigfast_(float x) {
    return __builtin_amdgcn_rcpf(1.0f + __expf(-x));
}
__device__ __forceinline__ float seluf_(float x) {
    const float sc = 1.0507009873554805f, al = 1.6732632423543772f;
    return x > 0.0f ? sc * x : sc * al * expm1f(x);
}
__device__ __forceinline__ unsigned short bf16_(float f) {
    union { float f; unsigned u; } c; c.f = f;
    unsigned u = c.u + 0x7fff + ((c.u >> 16) & 1);   // RNE
    return (unsigned short)(u >> 16);
}
__device__ __forceinline__ float f32_(unsigned short h) {
    union { unsigned u; float f; } c; c.u = ((unsigned)h) << 16;
    return c.f;
}
__device__ __forceinline__ void split_(float x, unsigned short& hi, unsigned short& lo) {
    hi = bf16_(x);
    lo = bf16_(x - f32_(hi));
}
__device__ __forceinline__ unsigned pk2_(float lo, float hi) {
    unsigned r;
    asm("v_cvt_pk_bf16_f32 %0, %1, %2" : "=v"(r) : "v"(lo), "v"(hi));
    return r;
}
__device__ __forceinline__ short8 pk8_(float4 a, float4 b) {
    union { unsigned u[4]; short8 s; } cv;
    cv.u[0] = pk2_(a.x, a.y); cv.u[1] = pk2_(a.z, a.w);
    cv.u[2] = pk2_(b.x, b.y); cv.u[3] = pk2_(b.z, b.w);
    return cv.s;
}
__device__ __forceinline__ short8 mulbf_(short8 a, short8 b) {
    union { unsigned u[4]; short8 s; } cv;
    #pragma unroll
    for (int i = 0; i < 4; ++i) {
        const float x0 = f32_((unsigned short)a[2*i])   * f32_((unsigned short)b[2*i]);
        const float x1 = f32_((unsigned short)a[2*i+1]) * f32_((unsigned short)b[2*i+1]);
        cv.u[i] = pk2_(x0, x1);
    }
    return cv.s;
}

// ---------------------------------------------------------------------------
// pk_all: prep, grid 3134 (unchanged from R7).
// ---------------------------------------------------------------------------
__global__ __launch_bounds__(256) void pk_all(
    const float* __restrict__ gate_w, const float* __restrict__ gate_b,
    const float* __restrict__ r2e,
    const float* __restrict__ ip_w, const float* __restrict__ op_w,
    const float* __restrict__ g1_w, const float* __restrict__ i2e,
    unsigned short* __restrict__ wfrag, float* __restrict__ cbuf,
    unsigned short* __restrict__ ipf_hi, unsigned short* __restrict__ ipf_lo,
    unsigned short* __restrict__ opf_hi, unsigned short* __restrict__ opf_lo,
    unsigned short* __restrict__ g1f,
    unsigned short* __restrict__ i2e_bf, unsigned short* __restrict__ r2e_bf)
{
    const int blk = blockIdx.x, tid = threadIdx.x;
    if (blk < 3125) {                                // i2e convert
        const int idx = blk * 256 + tid;
        const float4* s = reinterpret_cast<const float4*>(i2e);
        const float4 a = s[2 * idx], b = s[2 * idx + 1];
        reinterpret_cast<short8*>(i2e_bf)[idx] = pk8_(a, b);
        return;
    }
    const int pblk = blk - 3125;
    if (pblk < 4) {
        const int t = pblk * 256 + tid;
        const int rb = t >> 8, s = (t >> 6) & 3, l = t & 63;
        const int m = l & 15, h2 = m >> 2, q = m & 3;
        const int dim = (rb < 2) ? (8 * h2 + 4 * rb + q)
                                 : (32 + 8 * h2 + 4 * (rb - 2) + q);
        short8 o;
        #pragma unroll
        for (int j = 0; j < 8; ++j) {
            int k = 32 * s + 8 * (l >> 4) + j;
            int row = k + (k >= 64 ? 64 : 0);
            o[j] = (short)bf16_(gate_w[row * 64 + dim]);
        }
        reinterpret_cast<short8*>(wfrag)[t] = o;
    } else if (pblk == 4) {
        for (int i = tid; i < 384; i += 256) {
            int r = i >> 6, dim = i & 63;
            float acc = 0.0f;
            if (r < 5) {
                acc = gate_b[dim];
                for (int k = 0; k < 64; ++k)
                    acc = fmaf(r2e[r * 64 + k], gate_w[(64 + k) * 64 + dim], acc);
            }
            cbuf[i] = acc;
        }
    } else if (pblk == 5 || pblk == 6) {
        const float* W = (pblk == 5) ? ip_w : op_w;
        unsigned short* H = (pblk == 5) ? ipf_hi : opf_hi;
        unsigned short* Lo = (pblk == 5) ? ipf_lo : opf_lo;
        for (int e = tid; e < 512; e += 256) {
            int f = e >> 6, l = e & 63, s = f >> 2, nb = f & 3;
            short8 oh, ol;
            #pragma unroll
            for (int j = 0; j < 8; ++j) {
                float w = W[(32 * s + 8 * (l >> 4) + j) * 64 + 16 * nb + (l & 15)];
                unsigned short hi, lo; split_(w, hi, lo);
                oh[j] = (short)hi; ol[j] = (short)lo;
            }
            reinterpret_cast<short8*>(H)[e] = oh;
            reinterpret_cast<short8*>(Lo)[e] = ol;
        }
    } else if (pblk == 7) {
        for (int e = tid; e < 1536; e += 256) {
            int f = e >> 6, l = e & 63, s = f >> 2, nb = f & 3;
            short8 o;
            #pragma unroll
            for (int j = 0; j < 8; ++j)
                o[j] = (short)bf16_(g1_w[(32 * s + 8 * (l >> 4) + j) * 64 + 16 * nb + (l & 15)]);
            reinterpret_cast<short8*>(g1f)[e] = o;
        }
    } else {
        if (tid < 40) {
            const float4* s = reinterpret_cast<const float4*>(r2e);
            const float4 a = s[2 * tid], b = s[2 * tid + 1];
            reinterpret_cast<short8*>(r2e_bf)[tid] = pk8_(a, b);
        }
    }
}

// ---------------------------------------------------------------------------
// k1 v6 = R7 structure + fused stats-1 partials emission.
// ---------------------------------------------------------------------------
__global__ __launch_bounds__(256) void k1_fuse(
    const int* __restrict__ hist_ui, const int* __restrict__ hist_r,
    const unsigned short* __restrict__ i2e_bf,
    const unsigned short* __restrict__ r2e_bf,
    const unsigned short* __restrict__ wfrag, const float* __restrict__ cbuf,
    float* __restrict__ ws_att, float* __restrict__ partials1)
{
    __shared__ __align__(16) float sO[2][64 * 68];
    __shared__ __align__(16) float sPart[2][4][64];
    __shared__ float sVQ[2][64];

    const int b0  = blockIdx.x * 2;
    const int tid = threadIdx.x;
    const int wv  = tid >> 6;
    const int l   = tid & 63;
    const int h   = l >> 4;
    const int c16 = l & 15;

    const int row = wv * 16 + c16;
    const bool valid = row < L_;
    const float vm = valid ? 1.0f : 0.0f;

    const int iuA = valid ? hist_ui[b0 * L_ + row] : 0;
    const int rrA = valid ? hist_r[b0 * L_ + row] : 0;
    const int iuB = valid ? hist_ui[(b0 + 1) * L_ + row] : 0;
    const int rrB = valid ? hist_r[(b0 + 1) * L_ + row] : 0;

    const unsigned short* rA = i2e_bf + (size_t)iuA * 64;
    const unsigned short* rB = i2e_bf + (size_t)iuB * 64;
    const short8 euA0 = *reinterpret_cast<const short8*>(rA + 8 * h);
    const short8 euA1 = *reinterpret_cast<const short8*>(rA + 32 + 8 * h);
    const short8 euB0 = *reinterpret_cast<const short8*>(rB + 8 * h);
    const short8 euB1 = *reinterpret_cast<const short8*>(rB + 32 + 8 * h);

    const short8* wf = reinterpret_cast<const short8*>(wfrag);

    #pragma unroll
    for (int bb = 0; bb < 2; ++bb) {
        const short8 eu0 = bb ? euB0 : euA0;
        const short8 eu1 = bb ? euB1 : euA1;
        const int    rr  = bb ? rrB  : rrA;

        const unsigned short* rE = r2e_bf + rr * 64;
        const short8 er0 = *reinterpret_cast<const short8*>(rE + 8 * h);
        const short8 er1 = *reinterpret_cast<const short8*>(rE + 32 + 8 * h);

        short8 bfr[4];
        bfr[0] = eu0;
        bfr[1] = eu1;
        bfr[2] = mulbf_(eu0, er0);
        bfr[3] = mulbf_(eu1, er1);

        f32x4 acc[4];
        #pragma unroll
        for (int rb = 0; rb < 4; ++rb) acc[rb] = (f32x4){0.f, 0.f, 0.f, 0.f};
        #pragma unroll
        for (int s = 0; s < 4; ++s) {
            #pragma unroll
            for (int rb = 0; rb < 4; ++rb)
                acc[rb] = __builtin_amdgcn_mfma_f32_16x16x32_bf16(
                    wf[(rb * 4 + s) * 64 + l], bfr[s], acc[rb], 0, 0, 0);
        }

        float o[4][4];
        float ssq = 0.0f;
        #pragma unroll
        for (int rb = 0; rb < 4; ++rb) {
            const int cidx = (rb < 2) ? (2 * h + rb) : (8 + 2 * h + (rb - 2));
            const float4 cc = reinterpret_cast<const float4*>(cbuf)[rr * 16 + cidx];
            #pragma unroll
            for (int q = 0; q < 4; ++q) {
                const int e8 = (rb < 2) ? (4 * rb + q) : (4 * (rb - 2) + q);
                const float eu = (rb < 2) ? f32_((unsigned short)eu0[e8])
                                          : f32_((unsigned short)eu1[e8]);
                const float er = (rb < 2) ? f32_((unsigned short)er0[e8])
                                          : f32_((unsigned short)er1[e8]);
                const float a  = sigfast_(acc[rb][q] + (&cc.x)[q]);
                const float ov = (a * eu + (1.0f - a) * er) * vm;
                o[rb][q] = ov;
                ssq = fmaf(ov, ov, ssq);
            }
        }
        ssq += __shfl_xor(ssq, 16);
        ssq += __shfl_xor(ssq, 32);
        const float inv = __builtin_amdgcn_rsqf(fmaxf(ssq, 1e-24f));

        #pragma unroll
        for (int rb = 0; rb < 4; ++rb) {
            const int off = (rb < 2) ? (8 * h + 4 * rb) : (32 + 8 * h + 4 * (rb - 2));
            *reinterpret_cast<float4*>(&sO[bb][row * 68 + off]) =
                make_float4(o[rb][0] * inv, o[rb][1] * inv, o[rb][2] * inv, o[rb][3] * inv);
        }
    }
    __syncthreads();

    float tA = 0.0f, tB = 0.0f;
    #pragma unroll
    for (int i = 0; i < 16; ++i) {
        tA += sO[0][(wv * 16 + i) * 68 + l];
        tB += sO[1][(wv * 16 + i) * 68 + l];
    }
    sPart[0][wv][l] = tA;
    sPart[1][wv][l] = tB;
    __syncthreads();
    if (tid < 128) {
        const int bb = tid >> 6, d = tid & 63;
        const float v = sPart[bb][0][d] + sPart[bb][1][d] + sPart[bb][2][d] + sPart[bb][3][d];
        ws_att[(size_t)(b0 + bb) * D_ + d] = v;
        sVQ[bb][d] = v;
    }
    __syncthreads();
    if (tid < 64) {
        const float a = sVQ[0][tid], b2 = sVQ[1][tid];
        partials1[blockIdx.x * 128 + tid]      = a + b2;
        partials1[blockIdx.x * 128 + 64 + tid] = fmaf(a, a, b2 * b2);
    }
}

// ---------------------------------------------------------------------------
// k_tail: cooperative, 256 blocks x 256 (unchanged from R8).
// ---------------------------------------------------------------------------
__global__ __launch_bounds__(256) void k_tail(
    const float* __restrict__ partials1, float* __restrict__ p1b,
    const float* __restrict__ att,
    const float* __restrict__ bn_g, const float* __restrict__ bn_b,
    const unsigned short* __restrict__ ipf_hi, const unsigned short* __restrict__ ipf_lo,
    const float* __restrict__ ip_b,
    float* __restrict__ h1, float* __restrict__ partials2,
    const float* __restrict__ bn1_g, const float* __restrict__ bn1_b,
    const unsigned short* __restrict__ opf_hi, const unsigned short* __restrict__ opf_lo,
    const float* __restrict__ op_b,
    const int* __restrict__ nodes, const float* __restrict__ u2e,
    const unsigned short* __restrict__ g1f, const float* __restrict__ g1_b,
    float* __restrict__ out)
{
    __shared__ float sSt[128], sTmp[128], sP[4][128];
    __shared__ __align__(16) unsigned short sX3[4][16 * 200];

    cg::grid_group grid = cg::this_grid();
    const int blk = blockIdx.x, tid = threadIdx.x;
    const int wv = tid >> 6, l = tid & 63;
    const int h = l >> 4, c16 = l & 15;

    // ---- Phase A ----
    if (tid < 128) {
        float s = 0.f;
        #pragma unroll
        for (int r = 0; r < 8; ++r) s += partials1[(blk * 8 + r) * 128 + tid];
        p1b[blk * 128 + tid] = s;
    }
    grid.sync();

    // ---- Phase B: inproj ----
    if (blk < 64) {
        if (tid < 128) {
            float s = 0.f;
            for (int k = 0; k < 256; ++k) s += p1b[k * 128 + tid];
            sTmp[tid] = s;
        }
        __syncthreads();
        if (tid < 64) {
            const float m = sTmp[tid] * (1.0f / B_);
            const float var = fmaxf(sTmp[64 + tid] * (1.0f / B_) - m * m, 0.0f);
            const float istd = rsqrtf(var + 1e-5f);
            const float sc = istd * bn_g[tid];
            sSt[tid] = sc; sSt[64 + tid] = bn_b[tid] - m * sc;
        }
        __syncthreads();

        const int r0 = blk * 64 + wv * 16;
        const int row = r0 + c16;
        const float4* xr = reinterpret_cast<const float4*>(att + (size_t)row * 64);
        const float4 x0 = xr[2 * h], x1 = xr[2 * h + 1], x2 = xr[8 + 2 * h], x3v = xr[9 + 2 * h];
        const float4* st4 = reinterpret_cast<const float4*>(sSt);
        const float4 sc0 = st4[2 * h], sc1 = st4[2 * h + 1], sh0 = st4[16 + 2 * h], sh1 = st4[17 + 2 * h];
        const float4 sc2 = st4[8 + 2 * h], sc3 = st4[9 + 2 * h], sh2 = st4[24 + 2 * h], sh3 = st4[25 + 2 * h];

        float xn0[8], xn1[8];
        #pragma unroll
        for (int q = 0; q < 4; ++q) {
            xn0[q]     = fmaf((&x0.x)[q], (&sc0.x)[q], (&sh0.x)[q]);
            xn0[4 + q] = fmaf((&x1.x)[q], (&sc1.x)[q], (&sh1.x)[q]);
            xn1[q]     = fmaf((&x2.x)[q], (&sc2.x)[q], (&sh2.x)[q]);
            xn1[4 + q] = fmaf((&x3v.x)[q], (&sc3.x)[q], (&sh3.x)[q]);
        }
        short8 ah0, al0, ah1, al1;
        #pragma unroll
        for (int j = 0; j < 8; ++j) {
            unsigned short hi, lo;
            split_(xn0[j], hi, lo); ah0[j] = (short)hi; al0[j] = (short)lo;
            split_(xn1[j], hi, lo); ah1[j] = (short)hi; al1[j] = (short)lo;
        }

        f32x4 acc[4];
        #pragma unroll
        for (int nb = 0; nb < 4; ++nb) acc[nb] = (f32x4){0.f, 0.f, 0.f, 0.f};
        #pragma unroll
        for (int s = 0; s < 2; ++s) {
            const short8 aH = s ? ah1 : ah0;
            const short8 aL = s ? al1 : al0;
            #pragma unroll
            for (int nb = 0; nb < 4; ++nb) {
                const short8 bh = reinterpret_cast<const short8*>(ipf_hi)[(s * 4 + nb) * 64 + l];
                const short8 bl = reinterpret_cast<const short8*>(ipf_lo)[(s * 4 + nb) * 64 + l];
                acc[nb] = __builtin_amdgcn_mfma_f32_16x16x32_bf16(aH, bh, acc[nb], 0, 0, 0);
                acc[nb] = __builtin_amdgcn_mfma_f32_16x16x32_bf16(aL, bh, acc[nb], 0, 0, 0);
                acc[nb] = __builtin_amdgcn_mfma_f32_16x16x32_bf16(aH, bl, acc[nb], 0, 0, 0);
            }
        }

        #pragma unroll
        for (int nb = 0; nb < 4; ++nb) {
            const int dim = 16 * nb + c16;
            const float bias = ip_b[dim];
            float sl = 0.f, sq = 0.f;
            #pragma unroll
            for (int r = 0; r < 4; ++r) {
                const float v = seluf_(acc[nb][r] + bias);
                h1[(size_t)(r0 + 4 * h + r) * 64 + dim] = v;
                sl += v; sq = fmaf(v, v, sq);
            }
            sl += __shfl_xor(sl, 16); sl += __shfl_xor(sl, 32);
            sq += __shfl_xor(sq, 16); sq += __shfl_xor(sq, 32);
            if (l < 16) { sP[wv][16 * nb + l] = sl; sP[wv][64 + 16 * nb + l] = sq; }
        }
        __syncthreads();
        if (tid < 128)
            partials2[blk * 128 + tid] =
                sP[0][tid] + sP[1][tid] + sP[2][tid] + sP[3][tid];
    }
    grid.sync();

    // ---- Phase C: final ----
    if (blk < 64) {
        if (tid < 128) {
            float s = 0.f;
            for (int k = 0; k < 64; ++k) s += partials2[k * 128 + tid];
            sTmp[tid] = s;
        }
        __syncthreads();
        if (tid < 64) {
            const float m = sTmp[tid] * (1.0f / B_);
            const float var = fmaxf(sTmp[64 + tid] * (1.0f / B_) - m * m, 0.0f);
            const float istd = rsqrtf(var + 1e-5f);
            const float sc = istd * bn1_g[tid];
            sSt[tid] = sc; sSt[64 + tid] = bn1_b[tid] - m * sc;
        }
        __syncthreads();

        const int r0 = blk * 64 + wv * 16;
        const int row = r0 + c16;
        const float4* xr = reinterpret_cast<const float4*>(h1 + (size_t)row * 64);
        const float4 x0 = xr[2 * h], x1 = xr[2 * h + 1], x2 = xr[8 + 2 * h], x3v = xr[9 + 2 * h];
        const float4* st4 = reinterpret_cast<const float4*>(sSt);
        const float4 sc0 = st4[2 * h], sc1 = st4[2 * h + 1], sh0 = st4[16 + 2 * h], sh1 = st4[17 + 2 * h];
        const float4 sc2 = st4[8 + 2 * h], sc3 = st4[9 + 2 * h], sh2 = st4[24 + 2 * h], sh3 = st4[25 + 2 * h];

        float xn0[8], xn1[8];
        #pragma unroll
        for (int q = 0; q < 4; ++q) {
            xn0[q]     = fmaf((&x0.x)[q], (&sc0.x)[q], (&sh0.x)[q]);
            xn0[4 + q] = fmaf((&x1.x)[q], (&sc1.x)[q], (&sh1.x)[q]);
            xn1[q]     = fmaf((&x2.x)[q], (&sc2.x)[q], (&sh2.x)[q]);
            xn1[4 + q] = fmaf((&x3v.x)[q], (&sc3.x)[q], (&sh3.x)[q]);
        }
        short8 ah0, al0, ah1, al1;
        #pragma unroll
        for (int j = 0; j < 8; ++j) {
            unsigned short hi, lo;
            split_(xn0[j], hi, lo); ah0[j] = (short)hi; al0[j] = (short)lo;
            split_(xn1[j], hi, lo); ah1[j] = (short)hi; al1[j] = (short)lo;
        }

        f32x4 acc[4];
        #pragma unroll
        for (int nb = 0; nb < 4; ++nb) acc[nb] = (f32x4){0.f, 0.f, 0.f, 0.f};
        #pragma unroll
        for (int s = 0; s < 2; ++s) {
            const short8 aH = s ? ah1 : ah0;
            const short8 aL = s ? al1 : al0;
            #pragma unroll
            for (int nb = 0; nb < 4; ++nb) {
                const short8 bh = reinterpret_cast<const short8*>(opf_hi)[(s * 4 + nb) * 64 + l];
                const short8 bl = reinterpret_cast<const short8*>(opf_lo)[(s * 4 + nb) * 64 + l];
                acc[nb] = __builtin_amdgcn_mfma_f32_16x16x32_bf16(aH, bh, acc[nb], 0, 0, 0);
                acc[nb] = __builtin_amdgcn_mfma_f32_16x16x32_bf16(aL, bh, acc[nb], 0, 0, 0);
                acc[nb] = __builtin_amdgcn_mfma_f32_16x16x32_bf16(aH, bl, acc[nb], 0, 0, 0);
            }
        }

        int nd[4];
        #pragma unroll
        for (int r = 0; r < 4; ++r) nd[r] = nodes[r0 + 4 * h + r];

        float nn[4][4], sf[4][4];
        unsigned short* X = sX3[wv];
        #pragma unroll
        for (int nb = 0; nb < 4; ++nb) {
            const int dim = 16 * nb + c16;
            const float bias = op_b[dim];
            #pragma unroll
            for (int r = 0; r < 4; ++r) {
                const float v = acc[nb][r] + bias;
                const float s = u2e[(size_t)nd[r] * 64 + dim];
                nn[nb][r] = v; sf[nb][r] = s;
                const int rI = 4 * h + r;
                X[rI * 200 + dim]       = bf16_(s);
                X[rI * 200 + 64 + dim]  = bf16_(v);
                X[rI * 200 + 128 + dim] = bf16_(s * v);
            }
        }
        __syncthreads();

        f32x4 acc3[4];
        #pragma unroll
        for (int nb = 0; nb < 4; ++nb) acc3[nb] = (f32x4){0.f, 0.f, 0.f, 0.f};
        #pragma unroll
        for (int s = 0; s < 6; ++s) {
            const short8 a3 = *reinterpret_cast<const short8*>(&sX3[wv][c16 * 200 + 32 * s + 8 * h]);
            #pragma unroll
            for (int nb = 0; nb < 4; ++nb)
                acc3[nb] = __builtin_amdgcn_mfma_f32_16x16x32_bf16(
                    a3, reinterpret_cast<const short8*>(g1f)[(s * 4 + nb) * 64 + l], acc3[nb], 0, 0, 0);
        }

        #pragma unroll
        for (int nb = 0; nb < 4; ++nb) {
            const int dim = 16 * nb + c16;
            const float gb = g1_b[dim];
            #pragma unroll
            for (int r = 0; r < 4; ++r) {
                const float beta = sigfast_(acc3[nb][r] + gb);
                out[(size_t)(r0 + 4 * h + r) * 64 + dim] =
                    beta * sf[nb][r] + (1.0f - beta) * nn[nb][r];
            }
        }
    }
}

extern "C" void kernel_launch(void* const* d_in, const int* in_sizes, int n_in,
                              void* d_out, int out_size, void* d_ws, size_t ws_size,
                              hipStream_t stream) {
    (void)in_sizes; (void)n_in; (void)out_size; (void)ws_size;
    const int*   nodes     = (const int*)d_in[0];
    const int*   hist_ui   = (const int*)d_in[1];
    const int*   hist_r    = (const int*)d_in[2];
    const float* i2e_w     = (const float*)d_in[3];
    const float* u2e_w     = (const float*)d_in[4];
    const float* r2e_w     = (const float*)d_in[5];
    // d_in[6..13]: attention-score MLP params -- dead code (entmax over a
    // size-1 axis == 1.0 identically; head-1 renorm of unit vectors is identity).
    const float* gate_w    = (const float*)d_in[14];
    const float* gate_b    = (const float*)d_in[15];
    const float* gate1_w   = (const float*)d_in[16];
    const float* gate1_b   = (const float*)d_in[17];
    const float* bn_g      = (const float*)d_in[18];
    const float* bn_b      = (const float*)d_in[19];
    const float* inproj_w  = (const float*)d_in[20];
    const float* inproj_b  = (const float*)d_in[21];
    const float* bn1_g     = (const float*)d_in[22];
    const float* bn1_b     = (const float*)d_in[23];
    const float* outproj_w = (const float*)d_in[24];
    const float* outproj_b = (const float*)d_in[25];

    float* out = (float*)d_out;
    float* ws  = (float*)d_ws;
    // Float-offset workspace layout (non-overlapping; ~16.2 MB total):
    float* ws_att = ws;                              // [0, 262144)
    float* ws_h1  = ws + 262144;                     // [262144, 524288)
    float* cbuf   = ws + 524288;                     // [524288, 524672)
    unsigned short* wfrag  = (unsigned short*)(ws + 524672);  // 16 KB  -> ends 528768
    unsigned short* ipf_hi = (unsigned short*)(ws + 528768);  // 8 KB   -> 530816
    unsigned short* ipf_lo = (unsigned short*)(ws + 530816);  // 8 KB   -> 532864
    unsigned short* opf_hi = (unsigned short*)(ws + 532864);  // 8 KB   -> 534912
    unsigned short* opf_lo = (unsigned short*)(ws + 534912);  // 8 KB   -> 536960
    unsigned short* g1f    = (unsigned short*)(ws + 536960);  // 24 KB  -> 543104
    float* partials1 = ws + 543104;                  // 2048*128 -> ends 805248
    float* p1b       = ws + 805248;                  // 256*128  -> ends 838016
    float* partials2 = ws + 838016;                  // 64*128   -> ends 846208
    unsigned short* i2e_bf = (unsigned short*)(ws + 846208);   // 3.2M floats -> ends 4046208
    unsigned short* r2e_bf = (unsigned short*)(ws + 4046208);  // AFTER i2e_bf (R8 bug: overlapped)

    pk_all<<<3134, 256, 0, stream>>>(gate_w, gate_b, r2e_w, inproj_w, outproj_w,
                                     gate1_w, i2e_w, wfrag, cbuf, ipf_hi, ipf_lo,
                                     opf_hi, opf_lo, g1f, i2e_bf, r2e_bf);
    k1_fuse<<<B_ / 2, 256, 0, stream>>>(hist_ui, hist_r, i2e_bf, r2e_bf,
                                        wfrag, cbuf, ws_att, partials1);

    void* tailArgs[] = {
        (void*)&partials1, (void*)&p1b, (void*)&ws_att,
        (void*)&bn_g, (void*)&bn_b, (void*)&ipf_hi, (void*)&ipf_lo, (void*)&inproj_b,
        (void*)&ws_h1, (void*)&partials2,
        (void*)&bn1_g, (void*)&bn1_b, (void*)&opf_hi, (void*)&opf_lo, (void*)&outproj_b,
        (void*)&nodes, (void*)&u2e_w, (void*)&g1f, (void*)&gate1_b, (void*)&out
    };
    hipLaunchCooperativeKernel((const void*)k_tail, dim3(256), dim3(256),
                               tailArgs, 0, stream);
}

// Round 10
// 65.611 us; speedup vs baseline: 1.7821x; 1.7821x over previous
//
#include <hip/hip_runtime.h>
#include <hip/hip_bf16.h>

#define B_ 4096
#define L_ 50
#define D_ 64

typedef __attribute__((ext_vector_type(8))) short short8;
typedef __attribute__((ext_vector_type(4))) float f32x4;

__device__ __forceinline__ float sigfast_(float x) {
    return __builtin_amdgcn_rcpf(1.0f + __expf(-x));
}
__device__ __forceinline__ float seluf_(float x) {
    const float sc = 1.0507009873554805f, al = 1.6732632423543772f;
    return x > 0.0f ? sc * x : sc * al * expm1f(x);
}
__device__ __forceinline__ unsigned short bf16_(float f) {
    union { float f; unsigned u; } c; c.f = f;
    unsigned u = c.u + 0x7fff + ((c.u >> 16) & 1);   // RNE
    return (unsigned short)(u >> 16);
}
__device__ __forceinline__ float f32_(unsigned short h) {
    union { unsigned u; float f; } c; c.u = ((unsigned)h) << 16;
    return c.f;
}
__device__ __forceinline__ void split_(float x, unsigned short& hi, unsigned short& lo) {
    hi = bf16_(x);
    lo = bf16_(x - f32_(hi));
}
__device__ __forceinline__ unsigned pk2_(float lo, float hi) {
    unsigned r;
    asm("v_cvt_pk_bf16_f32 %0, %1, %2" : "=v"(r) : "v"(lo), "v"(hi));
    return r;
}
__device__ __forceinline__ short8 pk8_(float4 a, float4 b) {
    union { unsigned u[4]; short8 s; } cv;
    cv.u[0] = pk2_(a.x, a.y); cv.u[1] = pk2_(a.z, a.w);
    cv.u[2] = pk2_(b.x, b.y); cv.u[3] = pk2_(b.z, b.w);
    return cv.s;
}
__device__ __forceinline__ short8 mulbf_(short8 a, short8 b) {
    union { unsigned u[4]; short8 s; } cv;
    #pragma unroll
    for (int i = 0; i < 4; ++i) {
        const float x0 = f32_((unsigned short)a[2*i])   * f32_((unsigned short)b[2*i]);
        const float x1 = f32_((unsigned short)a[2*i+1]) * f32_((unsigned short)b[2*i+1]);
        cv.u[i] = pk2_(x0, x1);
    }
    return cv.s;
}

// ---------------------------------------------------------------------------
// pk_all: prep, grid 3134 (unchanged from R7).
// ---------------------------------------------------------------------------
__global__ __launch_bounds__(256) void pk_all(
    const float* __restrict__ gate_w, const float* __restrict__ gate_b,
    const float* __restrict__ r2e,
    const float* __restrict__ ip_w, const float* __restrict__ op_w,
    const float* __restrict__ g1_w, const float* __restrict__ i2e,
    unsigned short* __restrict__ wfrag, float* __restrict__ cbuf,
    unsigned short* __restrict__ ipf_hi, unsigned short* __restrict__ ipf_lo,
    unsigned short* __restrict__ opf_hi, unsigned short* __restrict__ opf_lo,
    unsigned short* __restrict__ g1f,
    unsigned short* __restrict__ i2e_bf, unsigned short* __restrict__ r2e_bf)
{
    const int blk = blockIdx.x, tid = threadIdx.x;
    if (blk < 3125) {                                // i2e convert
        const int idx = blk * 256 + tid;
        const float4* s = reinterpret_cast<const float4*>(i2e);
        const float4 a = s[2 * idx], b = s[2 * idx + 1];
        reinterpret_cast<short8*>(i2e_bf)[idx] = pk8_(a, b);
        return;
    }
    const int pblk = blk - 3125;
    if (pblk < 4) {
        const int t = pblk * 256 + tid;
        const int rb = t >> 8, s = (t >> 6) & 3, l = t & 63;
        const int m = l & 15, h2 = m >> 2, q = m & 3;
        const int dim = (rb < 2) ? (8 * h2 + 4 * rb + q)
                                 : (32 + 8 * h2 + 4 * (rb - 2) + q);
        short8 o;
        #pragma unroll
        for (int j = 0; j < 8; ++j) {
            int k = 32 * s + 8 * (l >> 4) + j;
            int row = k + (k >= 64 ? 64 : 0);
            o[j] = (short)bf16_(gate_w[row * 64 + dim]);
        }
        reinterpret_cast<short8*>(wfrag)[t] = o;
    } else if (pblk == 4) {
        for (int i = tid; i < 384; i += 256) {
            int r = i >> 6, dim = i & 63;
            float acc = 0.0f;
            if (r < 5) {
                acc = gate_b[dim];
                for (int k = 0; k < 64; ++k)
                    acc = fmaf(r2e[r * 64 + k], gate_w[(64 + k) * 64 + dim], acc);
            }
            cbuf[i] = acc;
        }
    } else if (pblk == 5 || pblk == 6) {
        const float* W = (pblk == 5) ? ip_w : op_w;
        unsigned short* H = (pblk == 5) ? ipf_hi : opf_hi;
        unsigned short* Lo = (pblk == 5) ? ipf_lo : opf_lo;
        for (int e = tid; e < 512; e += 256) {
            int f = e >> 6, l = e & 63, s = f >> 2, nb = f & 3;
            short8 oh, ol;
            #pragma unroll
            for (int j = 0; j < 8; ++j) {
                float w = W[(32 * s + 8 * (l >> 4) + j) * 64 + 16 * nb + (l & 15)];
                unsigned short hi, lo; split_(w, hi, lo);
                oh[j] = (short)hi; ol[j] = (short)lo;
            }
            reinterpret_cast<short8*>(H)[e] = oh;
            reinterpret_cast<short8*>(Lo)[e] = ol;
        }
    } else if (pblk == 7) {
        for (int e = tid; e < 1536; e += 256) {
            int f = e >> 6, l = e & 63, s = f >> 2, nb = f & 3;
            short8 o;
            #pragma unroll
            for (int j = 0; j < 8; ++j)
                o[j] = (short)bf16_(g1_w[(32 * s + 8 * (l >> 4) + j) * 64 + 16 * nb + (l & 15)]);
            reinterpret_cast<short8*>(g1f)[e] = o;
        }
    } else {
        if (tid < 40) {
            const float4* s = reinterpret_cast<const float4*>(r2e);
            const float4 a = s[2 * tid], b = s[2 * tid + 1];
            reinterpret_cast<short8*>(r2e_bf)[tid] = pk8_(a, b);
        }
    }
}

// ---------------------------------------------------------------------------
// k1 v6 = R7 structure + fused stats-1 partials emission (proven in R9).
// ---------------------------------------------------------------------------
__global__ __launch_bounds__(256) void k1_fuse(
    const int* __restrict__ hist_ui, const int* __restrict__ hist_r,
    const unsigned short* __restrict__ i2e_bf,
    const unsigned short* __restrict__ r2e_bf,
    const unsigned short* __restrict__ wfrag, const float* __restrict__ cbuf,
    float* __restrict__ ws_att, float* __restrict__ partials1)
{
    __shared__ __align__(16) float sO[2][64 * 68];
    __shared__ __align__(16) float sPart[2][4][64];
    __shared__ float sVQ[2][64];

    const int b0  = blockIdx.x * 2;
    const int tid = threadIdx.x;
    const int wv  = tid >> 6;
    const int l   = tid & 63;
    const int h   = l >> 4;
    const int c16 = l & 15;

    const int row = wv * 16 + c16;
    const bool valid = row < L_;
    const float vm = valid ? 1.0f : 0.0f;

    const int iuA = valid ? hist_ui[b0 * L_ + row] : 0;
    const int rrA = valid ? hist_r[b0 * L_ + row] : 0;
    const int iuB = valid ? hist_ui[(b0 + 1) * L_ + row] : 0;
    const int rrB = valid ? hist_r[(b0 + 1) * L_ + row] : 0;

    const unsigned short* rA = i2e_bf + (size_t)iuA * 64;
    const unsigned short* rB = i2e_bf + (size_t)iuB * 64;
    const short8 euA0 = *reinterpret_cast<const short8*>(rA + 8 * h);
    const short8 euA1 = *reinterpret_cast<const short8*>(rA + 32 + 8 * h);
    const short8 euB0 = *reinterpret_cast<const short8*>(rB + 8 * h);
    const short8 euB1 = *reinterpret_cast<const short8*>(rB + 32 + 8 * h);

    const short8* wf = reinterpret_cast<const short8*>(wfrag);

    #pragma unroll
    for (int bb = 0; bb < 2; ++bb) {
        const short8 eu0 = bb ? euB0 : euA0;
        const short8 eu1 = bb ? euB1 : euA1;
        const int    rr  = bb ? rrB  : rrA;

        const unsigned short* rE = r2e_bf + rr * 64;
        const short8 er0 = *reinterpret_cast<const short8*>(rE + 8 * h);
        const short8 er1 = *reinterpret_cast<const short8*>(rE + 32 + 8 * h);

        short8 bfr[4];
        bfr[0] = eu0;
        bfr[1] = eu1;
        bfr[2] = mulbf_(eu0, er0);
        bfr[3] = mulbf_(eu1, er1);

        f32x4 acc[4];
        #pragma unroll
        for (int rb = 0; rb < 4; ++rb) acc[rb] = (f32x4){0.f, 0.f, 0.f, 0.f};
        #pragma unroll
        for (int s = 0; s < 4; ++s) {
            #pragma unroll
            for (int rb = 0; rb < 4; ++rb)
                acc[rb] = __builtin_amdgcn_mfma_f32_16x16x32_bf16(
                    wf[(rb * 4 + s) * 64 + l], bfr[s], acc[rb], 0, 0, 0);
        }

        float o[4][4];
        float ssq = 0.0f;
        #pragma unroll
        for (int rb = 0; rb < 4; ++rb) {
            const int cidx = (rb < 2) ? (2 * h + rb) : (8 + 2 * h + (rb - 2));
            const float4 cc = reinterpret_cast<const float4*>(cbuf)[rr * 16 + cidx];
            #pragma unroll
            for (int q = 0; q < 4; ++q) {
                const int e8 = (rb < 2) ? (4 * rb + q) : (4 * (rb - 2) + q);
                const float eu = (rb < 2) ? f32_((unsigned short)eu0[e8])
                                          : f32_((unsigned short)eu1[e8]);
                const float er = (rb < 2) ? f32_((unsigned short)er0[e8])
                                          : f32_((unsigned short)er1[e8]);
                const float a  = sigfast_(acc[rb][q] + (&cc.x)[q]);
                const float ov = (a * eu + (1.0f - a) * er) * vm;
                o[rb][q] = ov;
                ssq = fmaf(ov, ov, ssq);
            }
        }
        ssq += __shfl_xor(ssq, 16);
        ssq += __shfl_xor(ssq, 32);
        const float inv = __builtin_amdgcn_rsqf(fmaxf(ssq, 1e-24f));

        #pragma unroll
        for (int rb = 0; rb < 4; ++rb) {
            const int off = (rb < 2) ? (8 * h + 4 * rb) : (32 + 8 * h + 4 * (rb - 2));
            *reinterpret_cast<float4*>(&sO[bb][row * 68 + off]) =
                make_float4(o[rb][0] * inv, o[rb][1] * inv, o[rb][2] * inv, o[rb][3] * inv);
        }
    }
    __syncthreads();

    float tA = 0.0f, tB = 0.0f;
    #pragma unroll
    for (int i = 0; i < 16; ++i) {
        tA += sO[0][(wv * 16 + i) * 68 + l];
        tB += sO[1][(wv * 16 + i) * 68 + l];
    }
    sPart[0][wv][l] = tA;
    sPart[1][wv][l] = tB;
    __syncthreads();
    if (tid < 128) {
        const int bb = tid >> 6, d = tid & 63;
        const float v = sPart[bb][0][d] + sPart[bb][1][d] + sPart[bb][2][d] + sPart[bb][3][d];
        ws_att[(size_t)(b0 + bb) * D_ + d] = v;
        sVQ[bb][d] = v;
    }
    __syncthreads();
    if (tid < 64) {
        const float a = sVQ[0][tid], b2 = sVQ[1][tid];
        partials1[blockIdx.x * 128 + tid]      = a + b2;
        partials1[blockIdx.x * 128 + 64 + tid] = fmaf(a, a, b2 * b2);
    }
}

// ---------------------------------------------------------------------------
// k_inproj: reduces partials1 (2048x128, L2-resident) -> BN stats, then
// h1 = selu(bn(att) @ inproj + b) via split-bf16 MFMA; emits partials2.
// 64 blocks x 256.
// ---------------------------------------------------------------------------
__global__ __launch_bounds__(256) void k_inproj(
    const float* __restrict__ att, const float* __restrict__ partials1,
    const float* __restrict__ bn_g, const float* __restrict__ bn_b,
    const unsigned short* __restrict__ ipf_hi, const unsigned short* __restrict__ ipf_lo,
    const float* __restrict__ ip_b,
    float* __restrict__ h1, float* __restrict__ partials2)
{
    __shared__ float sSt[128], sTmp[128], sP[4][128];
    __shared__ float sRed[2][128];
    const int tid = threadIdx.x, wv = tid >> 6, l = tid & 63;
    const int h = l >> 4, c16 = l & 15;

    // ---- reduce 2048 partial rows (2-way thread split, 4 accumulators) ----
    {
        const int col = tid & 127, half = tid >> 7;
        const float* p = partials1 + (size_t)half * 1024 * 128 + col;
        float s0 = 0.f, s1 = 0.f, s2 = 0.f, s3 = 0.f;
        for (int k = 0; k < 1024; k += 4) {
            s0 += p[(k + 0) * 128]; s1 += p[(k + 1) * 128];
            s2 += p[(k + 2) * 128]; s3 += p[(k + 3) * 128];
        }
        sRed[half][col] = (s0 + s1) + (s2 + s3);
    }
    __syncthreads();
    if (tid < 128) sTmp[tid] = sRed[0][tid] + sRed[1][tid];
    __syncthreads();
    if (tid < 64) {
        const float m = sTmp[tid] * (1.0f / B_);
        const float var = fmaxf(sTmp[64 + tid] * (1.0f / B_) - m * m, 0.0f);
        const float istd = rsqrtf(var + 1e-5f);
        const float sc = istd * bn_g[tid];
        sSt[tid] = sc; sSt[64 + tid] = bn_b[tid] - m * sc;
    }
    __syncthreads();

    const int r0 = blockIdx.x * 64 + wv * 16;
    const int row = r0 + c16;
    const float4* xr = reinterpret_cast<const float4*>(att + (size_t)row * 64);
    const float4 x0 = xr[2 * h], x1 = xr[2 * h + 1], x2 = xr[8 + 2 * h], x3v = xr[9 + 2 * h];
    const float4* st4 = reinterpret_cast<const float4*>(sSt);
    const float4 sc0 = st4[2 * h], sc1 = st4[2 * h + 1], sh0 = st4[16 + 2 * h], sh1 = st4[17 + 2 * h];
    const float4 sc2 = st4[8 + 2 * h], sc3 = st4[9 + 2 * h], sh2 = st4[24 + 2 * h], sh3 = st4[25 + 2 * h];

    float xn0[8], xn1[8];
    #pragma unroll
    for (int q = 0; q < 4; ++q) {
        xn0[q]     = fmaf((&x0.x)[q], (&sc0.x)[q], (&sh0.x)[q]);
        xn0[4 + q] = fmaf((&x1.x)[q], (&sc1.x)[q], (&sh1.x)[q]);
        xn1[q]     = fmaf((&x2.x)[q], (&sc2.x)[q], (&sh2.x)[q]);
        xn1[4 + q] = fmaf((&x3v.x)[q], (&sc3.x)[q], (&sh3.x)[q]);
    }
    short8 ah0, al0, ah1, al1;
    #pragma unroll
    for (int j = 0; j < 8; ++j) {
        unsigned short hi, lo;
        split_(xn0[j], hi, lo); ah0[j] = (short)hi; al0[j] = (short)lo;
        split_(xn1[j], hi, lo); ah1[j] = (short)hi; al1[j] = (short)lo;
    }

    f32x4 acc[4];
    #pragma unroll
    for (int nb = 0; nb < 4; ++nb) acc[nb] = (f32x4){0.f, 0.f, 0.f, 0.f};
    #pragma unroll
    for (int s = 0; s < 2; ++s) {
        const short8 aH = s ? ah1 : ah0;
        const short8 aL = s ? al1 : al0;
        #pragma unroll
        for (int nb = 0; nb < 4; ++nb) {
            const short8 bh = reinterpret_cast<const short8*>(ipf_hi)[(s * 4 + nb) * 64 + l];
            const short8 bl = reinterpret_cast<const short8*>(ipf_lo)[(s * 4 + nb) * 64 + l];
            acc[nb] = __builtin_amdgcn_mfma_f32_16x16x32_bf16(aH, bh, acc[nb], 0, 0, 0);
            acc[nb] = __builtin_amdgcn_mfma_f32_16x16x32_bf16(aL, bh, acc[nb], 0, 0, 0);
            acc[nb] = __builtin_amdgcn_mfma_f32_16x16x32_bf16(aH, bl, acc[nb], 0, 0, 0);
        }
    }

    #pragma unroll
    for (int nb = 0; nb < 4; ++nb) {
        const int dim = 16 * nb + c16;
        const float bias = ip_b[dim];
        float sl = 0.f, sq = 0.f;
        #pragma unroll
        for (int r = 0; r < 4; ++r) {
            const float v = seluf_(acc[nb][r] + bias);
            h1[(size_t)(r0 + 4 * h + r) * 64 + dim] = v;
            sl += v; sq = fmaf(v, v, sq);
        }
        sl += __shfl_xor(sl, 16); sl += __shfl_xor(sl, 32);
        sq += __shfl_xor(sq, 16); sq += __shfl_xor(sq, 32);
        if (l < 16) { sP[wv][16 * nb + l] = sl; sP[wv][64 + 16 * nb + l] = sq; }
    }
    __syncthreads();
    if (tid < 128)
        partials2[blockIdx.x * 128 + tid] =
            sP[0][tid] + sP[1][tid] + sP[2][tid] + sP[3][tid];
}

// ---------------------------------------------------------------------------
// k_final: reduces partials2 (64x128) -> BN1 stats; n = bn1(h1)@outproj+b;
// beta via gate1 (bf16); out = beta*self + (1-beta)*n. 64 blocks x 256.
// ---------------------------------------------------------------------------
__global__ __launch_bounds__(256) void k_final(
    const float* __restrict__ h1, const float* __restrict__ partials2,
    const float* __restrict__ bn1_g, const float* __restrict__ bn1_b,
    const unsigned short* __restrict__ opf_hi, const unsigned short* __restrict__ opf_lo,
    const float* __restrict__ op_b,
    const int* __restrict__ nodes, const float* __restrict__ u2e,
    const unsigned short* __restrict__ g1f, const float* __restrict__ g1_b,
    float* __restrict__ out)
{
    __shared__ float sSt[128], sTmp[128];
    __shared__ __align__(16) unsigned short sX3[4][16 * 200];
    const int tid = threadIdx.x, wv = tid >> 6, l = tid & 63;
    const int h = l >> 4, c16 = l & 15;

    if (tid < 128) {
        float s = 0.f;
        #pragma unroll 8
        for (int k = 0; k < 64; ++k) s += partials2[k * 128 + tid];
        sTmp[tid] = s;
    }
    __syncthreads();
    if (tid < 64) {
        const float m = sTmp[tid] * (1.0f / B_);
        const float var = fmaxf(sTmp[64 + tid] * (1.0f / B_) - m * m, 0.0f);
        const float istd = rsqrtf(var + 1e-5f);
        const float sc = istd * bn1_g[tid];
        sSt[tid] = sc; sSt[64 + tid] = bn1_b[tid] - m * sc;
    }
    __syncthreads();

    const int r0 = blockIdx.x * 64 + wv * 16;
    const int row = r0 + c16;
    const float4* xr = reinterpret_cast<const float4*>(h1 + (size_t)row * 64);
    const float4 x0 = xr[2 * h], x1 = xr[2 * h + 1], x2 = xr[8 + 2 * h], x3v = xr[9 + 2 * h];
    const float4* st4 = reinterpret_cast<const float4*>(sSt);
    const float4 sc0 = st4[2 * h], sc1 = st4[2 * h + 1], sh0 = st4[16 + 2 * h], sh1 = st4[17 + 2 * h];
    const float4 sc2 = st4[8 + 2 * h], sc3 = st4[9 + 2 * h], sh2 = st4[24 + 2 * h], sh3 = st4[25 + 2 * h];

    float xn0[8], xn1[8];
    #pragma unroll
    for (int q = 0; q < 4; ++q) {
        xn0[q]     = fmaf((&x0.x)[q], (&sc0.x)[q], (&sh0.x)[q]);
        xn0[4 + q] = fmaf((&x1.x)[q], (&sc1.x)[q], (&sh1.x)[q]);
        xn1[q]     = fmaf((&x2.x)[q], (&sc2.x)[q], (&sh2.x)[q]);
        xn1[4 + q] = fmaf((&x3v.x)[q], (&sc3.x)[q], (&sh3.x)[q]);
    }
    short8 ah0, al0, ah1, al1;
    #pragma unroll
    for (int j = 0; j < 8; ++j) {
        unsigned short hi, lo;
        split_(xn0[j], hi, lo); ah0[j] = (short)hi; al0[j] = (short)lo;
        split_(xn1[j], hi, lo); ah1[j] = (short)hi; al1[j] = (short)lo;
    }

    f32x4 acc[4];
    #pragma unroll
    for (int nb = 0; nb < 4; ++nb) acc[nb] = (f32x4){0.f, 0.f, 0.f, 0.f};
    #pragma unroll
    for (int s = 0; s < 2; ++s) {
        const short8 aH = s ? ah1 : ah0;
        const short8 aL = s ? al1 : al0;
        #pragma unroll
        for (int nb = 0; nb < 4; ++nb) {
            const short8 bh = reinterpret_cast<const short8*>(opf_hi)[(s * 4 + nb) * 64 + l];
            const short8 bl = reinterpret_cast<const short8*>(opf_lo)[(s * 4 + nb) * 64 + l];
            acc[nb] = __builtin_amdgcn_mfma_f32_16x16x32_bf16(aH, bh, acc[nb], 0, 0, 0);
            acc[nb] = __builtin_amdgcn_mfma_f32_16x16x32_bf16(aL, bh, acc[nb], 0, 0, 0);
            acc[nb] = __builtin_amdgcn_mfma_f32_16x16x32_bf16(aH, bl, acc[nb], 0, 0, 0);
        }
    }

    int nd[4];
    #pragma unroll
    for (int r = 0; r < 4; ++r) nd[r] = nodes[r0 + 4 * h + r];

    float nn[4][4], sf[4][4];
    unsigned short* X = sX3[wv];
    #pragma unroll
    for (int nb = 0; nb < 4; ++nb) {
        const int dim = 16 * nb + c16;
        const float bias = op_b[dim];
        #pragma unroll
        for (int r = 0; r < 4; ++r) {
            const float v = acc[nb][r] + bias;
            const float s = u2e[(size_t)nd[r] * 64 + dim];
            nn[nb][r] = v; sf[nb][r] = s;
            const int rI = 4 * h + r;
            X[rI * 200 + dim]       = bf16_(s);
            X[rI * 200 + 64 + dim]  = bf16_(v);
            X[rI * 200 + 128 + dim] = bf16_(s * v);
        }
    }
    __builtin_amdgcn_wave_barrier();
    __syncthreads();

    f32x4 acc3[4];
    #pragma unroll
    for (int nb = 0; nb < 4; ++nb) acc3[nb] = (f32x4){0.f, 0.f, 0.f, 0.f};
    #pragma unroll
    for (int s = 0; s < 6; ++s) {
        const short8 a3 = *reinterpret_cast<const short8*>(&sX3[wv][c16 * 200 + 32 * s + 8 * h]);
        #pragma unroll
        for (int nb = 0; nb < 4; ++nb)
            acc3[nb] = __builtin_amdgcn_mfma_f32_16x16x32_bf16(
                a3, reinterpret_cast<const short8*>(g1f)[(s * 4 + nb) * 64 + l], acc3[nb], 0, 0, 0);
    }

    #pragma unroll
    for (int nb = 0; nb < 4; ++nb) {
        const int dim = 16 * nb + c16;
        const float gb = g1_b[dim];
        #pragma unroll
        for (int r = 0; r < 4; ++r) {
            const float beta = sigfast_(acc3[nb][r] + gb);
            out[(size_t)(r0 + 4 * h + r) * 64 + dim] =
                beta * sf[nb][r] + (1.0f - beta) * nn[nb][r];
        }
    }
}

extern "C" void kernel_launch(void* const* d_in, const int* in_sizes, int n_in,
                              void* d_out, int out_size, void* d_ws, size_t ws_size,
                              hipStream_t stream) {
    (void)in_sizes; (void)n_in; (void)out_size; (void)ws_size;
    const int*   nodes     = (const int*)d_in[0];
    const int*   hist_ui   = (const int*)d_in[1];
    const int*   hist_r    = (const int*)d_in[2];
    const float* i2e_w     = (const float*)d_in[3];
    const float* u2e_w     = (const float*)d_in[4];
    const float* r2e_w     = (const float*)d_in[5];
    // d_in[6..13]: attention-score MLP params -- dead code (entmax over a
    // size-1 axis == 1.0 identically; head-1 renorm of unit vectors is identity).
    const float* gate_w    = (const float*)d_in[14];
    const float* gate_b    = (const float*)d_in[15];
    const float* gate1_w   = (const float*)d_in[16];
    const float* gate1_b   = (const float*)d_in[17];
    const float* bn_g      = (const float*)d_in[18];
    const float* bn_b      = (const float*)d_in[19];
    const float* inproj_w  = (const float*)d_in[20];
    const float* inproj_b  = (const float*)d_in[21];
    const float* bn1_g     = (const float*)d_in[22];
    const float* bn1_b     = (const float*)d_in[23];
    const float* outproj_w = (const float*)d_in[24];
    const float* outproj_b = (const float*)d_in[25];

    float* out = (float*)d_out;
    float* ws  = (float*)d_ws;
    // Float-offset workspace layout (non-overlapping; ~16.2 MB total):
    float* ws_att = ws;                              // [0, 262144)
    float* ws_h1  = ws + 262144;                     // [262144, 524288)
    float* cbuf   = ws + 524288;                     // [524288, 524672)
    unsigned short* wfrag  = (unsigned short*)(ws + 524672);  // 16 KB  -> ends 528768
    unsigned short* ipf_hi = (unsigned short*)(ws + 528768);  // 8 KB   -> 530816
    unsigned short* ipf_lo = (unsigned short*)(ws + 530816);  // 8 KB   -> 532864
    unsigned short* opf_hi = (unsigned short*)(ws + 532864);  // 8 KB   -> 534912
    unsigned short* opf_lo = (unsigned short*)(ws + 534912);  // 8 KB   -> 536960
    unsigned short* g1f    = (unsigned short*)(ws + 536960);  // 24 KB  -> 543104
    float* partials1 = ws + 543104;                  // 2048*128 -> ends 805248
    float* partials2 = ws + 805248;                  // 64*128   -> ends 813440
    unsigned short* i2e_bf = (unsigned short*)(ws + 813440);   // 3.2M floats -> ends 4013440
    unsigned short* r2e_bf = (unsigned short*)(ws + 4013440);  // after i2e_bf

    pk_all<<<3134, 256, 0, stream>>>(gate_w, gate_b, r2e_w, inproj_w, outproj_w,
                                     gate1_w, i2e_w, wfrag, cbuf, ipf_hi, ipf_lo,
                                     opf_hi, opf_lo, g1f, i2e_bf, r2e_bf);
    k1_fuse<<<B_ / 2, 256, 0, stream>>>(hist_ui, hist_r, i2e_bf, r2e_bf,
                                        wfrag, cbuf, ws_att, partials1);
    k_inproj<<<64, 256, 0, stream>>>(ws_att, partials1, bn_g, bn_b, ipf_hi, ipf_lo,
                                     inproj_b, ws_h1, partials2);
    k_final<<<64, 256, 0, stream>>>(ws_h1, partials2, bn1_g, bn1_b, opf_hi, opf_lo,
                                    outproj_b, nodes, u2e_w, g1f, gate1_b, out);
}

// Round 11
// 53.622 us; speedup vs baseline: 2.1806x; 1.2236x over previous
//
#include <hip/hip_runtime.h>
#include <hip/hip_bf16.h>

#define B_ 4096
#define L_ 50
#define D_ 64

typedef __attribute__((ext_vector_type(8))) short short8;
typedef __attribute__((ext_vector_type(4))) float f32x4;

__device__ __forceinline__ float sigfast_(float x) {
    return __builtin_amdgcn_rcpf(1.0f + __expf(-x));
}
__device__ __forceinline__ float seluf_(float x) {
    const float sc = 1.0507009873554805f, al = 1.6732632423543772f;
    return x > 0.0f ? sc * x : sc * al * expm1f(x);
}
__device__ __forceinline__ unsigned short bf16_(float f) {
    union { float f; unsigned u; } c; c.f = f;
    unsigned u = c.u + 0x7fff + ((c.u >> 16) & 1);   // RNE
    return (unsigned short)(u >> 16);
}
__device__ __forceinline__ float f32_(unsigned short h) {
    union { unsigned u; float f; } c; c.u = ((unsigned)h) << 16;
    return c.f;
}
__device__ __forceinline__ void split_(float x, unsigned short& hi, unsigned short& lo) {
    hi = bf16_(x);
    lo = bf16_(x - f32_(hi));
}
__device__ __forceinline__ unsigned pk2_(float lo, float hi) {
    unsigned r;
    asm("v_cvt_pk_bf16_f32 %0, %1, %2" : "=v"(r) : "v"(lo), "v"(hi));
    return r;
}
__device__ __forceinline__ short8 pk8_(float4 a, float4 b) {
    union { unsigned u[4]; short8 s; } cv;
    cv.u[0] = pk2_(a.x, a.y); cv.u[1] = pk2_(a.z, a.w);
    cv.u[2] = pk2_(b.x, b.y); cv.u[3] = pk2_(b.z, b.w);
    return cv.s;
}

// ---------------------------------------------------------------------------
// pk_all: prep, 8 blocks only (no embedding-table conversion).
//  blk 0-3: gate A-frags (PERMUTED m-packing, as R7)
//  blk 4  : cbuf[r][d] = gate_b[d] + e_r[r] @ W2
//  blk 5/6: inproj/outproj hi-lo split frags
//  blk 7  : gate1 frags
// ---------------------------------------------------------------------------
__global__ __launch_bounds__(256) void pk_all(
    const float* __restrict__ gate_w, const float* __restrict__ gate_b,
    const float* __restrict__ r2e,
    const float* __restrict__ ip_w, const float* __restrict__ op_w,
    const float* __restrict__ g1_w,
    unsigned short* __restrict__ wfrag, float* __restrict__ cbuf,
    unsigned short* __restrict__ ipf_hi, unsigned short* __restrict__ ipf_lo,
    unsigned short* __restrict__ opf_hi, unsigned short* __restrict__ opf_lo,
    unsigned short* __restrict__ g1f)
{
    const int pblk = blockIdx.x, tid = threadIdx.x;
    if (pblk < 4) {
        const int t = pblk * 256 + tid;
        const int rb = t >> 8, s = (t >> 6) & 3, l = t & 63;
        const int m = l & 15, h2 = m >> 2, q = m & 3;
        const int dim = (rb < 2) ? (8 * h2 + 4 * rb + q)
                                 : (32 + 8 * h2 + 4 * (rb - 2) + q);
        short8 o;
        #pragma unroll
        for (int j = 0; j < 8; ++j) {
            int k = 32 * s + 8 * (l >> 4) + j;      // 0..127
            int row = k + (k >= 64 ? 64 : 0);       // W1 rows 0..63, W3 rows 128..191
            o[j] = (short)bf16_(gate_w[row * 64 + dim]);
        }
        reinterpret_cast<short8*>(wfrag)[t] = o;
    } else if (pblk == 4) {
        for (int i = tid; i < 384; i += 256) {
            int r = i >> 6, dim = i & 63;
            float acc = 0.0f;
            if (r < 5) {
                acc = gate_b[dim];
                for (int k = 0; k < 64; ++k)
                    acc = fmaf(r2e[r * 64 + k], gate_w[(64 + k) * 64 + dim], acc);
            }
            cbuf[i] = acc;
        }
    } else if (pblk == 5 || pblk == 6) {
        const float* W = (pblk == 5) ? ip_w : op_w;
        unsigned short* H = (pblk == 5) ? ipf_hi : opf_hi;
        unsigned short* Lo = (pblk == 5) ? ipf_lo : opf_lo;
        for (int e = tid; e < 512; e += 256) {
            int f = e >> 6, l = e & 63, s = f >> 2, nb = f & 3;
            short8 oh, ol;
            #pragma unroll
            for (int j = 0; j < 8; ++j) {
                float w = W[(32 * s + 8 * (l >> 4) + j) * 64 + 16 * nb + (l & 15)];
                unsigned short hi, lo; split_(w, hi, lo);
                oh[j] = (short)hi; ol[j] = (short)lo;
            }
            reinterpret_cast<short8*>(H)[e] = oh;
            reinterpret_cast<short8*>(Lo)[e] = ol;
        }
    } else {
        for (int e = tid; e < 1536; e += 256) {
            int f = e >> 6, l = e & 63, s = f >> 2, nb = f & 3;
            short8 o;
            #pragma unroll
            for (int j = 0; j < 8; ++j)
                o[j] = (short)bf16_(g1_w[(32 * s + 8 * (l >> 4) + j) * 64 + 16 * nb + (l & 15)]);
            reinterpret_cast<short8*>(g1f)[e] = o;
        }
    }
}

// ---------------------------------------------------------------------------
// k1 v7: R7 structure with DIRECT fp32 i2e gather (no pre-converted table).
// 2 batches/block (grid 2048); ALL 8 scattered float4 gathers up-front (max
// MLP); in-register v_cvt_pk_bf16_f32 for B-frags; fp32 epilogue from the
// same registers (zero re-reads). Single sO buffer -> LDS 18.4 KB ->
// 8 blocks/CU (2x occupancy vs R7).
// ---------------------------------------------------------------------------
__global__ __launch_bounds__(256) void k1_fuse(
    const int* __restrict__ hist_ui, const int* __restrict__ hist_r,
    const float* __restrict__ i2e, const float* __restrict__ r2e,
    const unsigned short* __restrict__ wfrag, const float* __restrict__ cbuf,
    float* __restrict__ ws_att)
{
    __shared__ __align__(16) float sO[64 * 68];     // 17.4 KB
    __shared__ __align__(16) float sPart[4][64];    // 1 KB

    const int b0  = blockIdx.x * 2;
    const int tid = threadIdx.x;
    const int wv  = tid >> 6;
    const int l   = tid & 63;
    const int h   = l >> 4;
    const int c16 = l & 15;

    const int row = wv * 16 + c16;
    const bool valid = row < L_;
    const float vm = valid ? 1.0f : 0.0f;

    const int iuA = valid ? hist_ui[b0 * L_ + row] : 0;
    const int rrA = valid ? hist_r[b0 * L_ + row] : 0;
    const int iuB = valid ? hist_ui[(b0 + 1) * L_ + row] : 0;
    const int rrB = valid ? hist_r[(b0 + 1) * L_ + row] : 0;

    // ---- issue ALL scattered fp32 gathers up-front (8 independent loads) ----
    const float4* gA = reinterpret_cast<const float4*>(i2e + (size_t)iuA * D_);
    const float4* gB = reinterpret_cast<const float4*>(i2e + (size_t)iuB * D_);
    const float4 fA0 = gA[2 * h],     fA1 = gA[2 * h + 1];
    const float4 fA2 = gA[8 + 2 * h], fA3 = gA[9 + 2 * h];
    const float4 fB0 = gB[2 * h],     fB1 = gB[2 * h + 1];
    const float4 fB2 = gB[8 + 2 * h], fB3 = gB[9 + 2 * h];

    const short8* wf = reinterpret_cast<const short8*>(wfrag);

    #pragma unroll
    for (int bb = 0; bb < 2; ++bb) {
        const float4 e0 = bb ? fB0 : fA0;
        const float4 e1 = bb ? fB1 : fA1;
        const float4 e2 = bb ? fB2 : fA2;
        const float4 e3 = bb ? fB3 : fA3;
        const int    rr = bb ? rrB  : rrA;

        const float4* rp = reinterpret_cast<const float4*>(r2e + rr * D_); // L1-hot
        const float4 r0 = rp[2 * h],     r1 = rp[2 * h + 1];
        const float4 r2 = rp[8 + 2 * h], r3 = rp[9 + 2 * h];

        const float4 p0 = make_float4(e0.x*r0.x, e0.y*r0.y, e0.z*r0.z, e0.w*r0.w);
        const float4 p1 = make_float4(e1.x*r1.x, e1.y*r1.y, e1.z*r1.z, e1.w*r1.w);
        const float4 p2 = make_float4(e2.x*r2.x, e2.y*r2.y, e2.z*r2.z, e2.w*r2.w);
        const float4 p3 = make_float4(e3.x*r3.x, e3.y*r3.y, e3.z*r3.z, e3.w*r3.w);

        short8 bfr[4];
        bfr[0] = pk8_(e0, e1);          // k-slice [8h, 8h+8)        (e_ui)
        bfr[1] = pk8_(e2, e3);          // k-slice [32+8h, 32+8h+8)  (e_ui)
        bfr[2] = pk8_(p0, p1);          // product slice 1
        bfr[3] = pk8_(p2, p3);          // product slice 2

        // ---- 16 MFMAs (A-frags L1/L2-hot) ----
        f32x4 acc[4];
        #pragma unroll
        for (int rb = 0; rb < 4; ++rb) acc[rb] = (f32x4){0.f, 0.f, 0.f, 0.f};
        #pragma unroll
        for (int s = 0; s < 4; ++s) {
            #pragma unroll
            for (int rb = 0; rb < 4; ++rb)
                acc[rb] = __builtin_amdgcn_mfma_f32_16x16x32_bf16(
                    wf[(rb * 4 + s) * 64 + l], bfr[s], acc[rb], 0, 0, 0);
        }

        // ---- epilogue: dims == frag-register dims; fp32 operands ----
        float o[4][4];
        float ssq = 0.0f;
        #pragma unroll
        for (int rb = 0; rb < 4; ++rb) {
            const float4 eu4 = (rb == 0) ? e0 : (rb == 1) ? e1 : (rb == 2) ? e2 : e3;
            const float4 er4 = (rb == 0) ? r0 : (rb == 1) ? r1 : (rb == 2) ? r2 : r3;
            const int cidx = (rb < 2) ? (2 * h + rb) : (8 + 2 * h + (rb - 2));
            const float4 cc = reinterpret_cast<const float4*>(cbuf)[rr * 16 + cidx];
            #pragma unroll
            for (int q = 0; q < 4; ++q) {
                const float a  = sigfast_(acc[rb][q] + (&cc.x)[q]);
                const float ov = (a * (&eu4.x)[q] + (1.0f - a) * (&er4.x)[q]) * vm;
                o[rb][q] = ov;
                ssq = fmaf(ov, ov, ssq);
            }
        }
        ssq += __shfl_xor(ssq, 16);
        ssq += __shfl_xor(ssq, 32);
        const float inv = __builtin_amdgcn_rsqf(fmaxf(ssq, 1e-24f));

        // ---- store normalized slices; transpose-reduce this batch ----
        #pragma unroll
        for (int rb = 0; rb < 4; ++rb) {
            const int off = (rb < 2) ? (8 * h + 4 * rb) : (32 + 8 * h + 4 * (rb - 2));
            *reinterpret_cast<float4*>(&sO[row * 68 + off]) =
                make_float4(o[rb][0] * inv, o[rb][1] * inv, o[rb][2] * inv, o[rb][3] * inv);
        }
        __syncthreads();
        float t = 0.0f;
        #pragma unroll
        for (int i = 0; i < 16; ++i) t += sO[(wv * 16 + i) * 68 + l];
        sPart[wv][l] = t;
        __syncthreads();
        if (tid < 64)
            ws_att[(size_t)(b0 + bb) * D_ + tid] =
                sPart[0][tid] + sPart[1][tid] + sPart[2][tid] + sPart[3][tid];
        // next iteration's sO writes are ordered after this sync; sPart is
        // rewritten only after the next iteration's own __syncthreads.
    }
}

// ---------------------------------------------------------------------------
// k_statsP: coalesced partial sums/sumsq per dim.  32 blocks x 256 (R7).
// ---------------------------------------------------------------------------
__global__ __launch_bounds__(256) void k_statsP(const float* __restrict__ x,
                                                float* __restrict__ part)
{
    __shared__ float sA[4][16][8];
    const int tid = threadIdx.x, wv = tid >> 6, l = tid & 63;
    float4 s4 = make_float4(0, 0, 0, 0), q4 = make_float4(0, 0, 0, 0);
    const float4* xv = reinterpret_cast<const float4*>(x);
    const int base = blockIdx.x * 2048 + tid;
    #pragma unroll
    for (int k = 0; k < 8; ++k) {
        float4 v = xv[base + 256 * k];
        s4.x += v.x; s4.y += v.y; s4.z += v.z; s4.w += v.w;
        q4.x = fmaf(v.x, v.x, q4.x); q4.y = fmaf(v.y, v.y, q4.y);
        q4.z = fmaf(v.z, v.z, q4.z); q4.w = fmaf(v.w, v.w, q4.w);
    }
    #define RED_(f) f += __shfl_xor(f, 16); f += __shfl_xor(f, 32);
    RED_(s4.x) RED_(s4.y) RED_(s4.z) RED_(s4.w)
    RED_(q4.x) RED_(q4.y) RED_(q4.z) RED_(q4.w)
    #undef RED_
    if (l < 16) {
        sA[wv][l][0] = s4.x; sA[wv][l][1] = s4.y; sA[wv][l][2] = s4.z; sA[wv][l][3] = s4.w;
        sA[wv][l][4] = q4.x; sA[wv][l][5] = q4.y; sA[wv][l][6] = q4.z; sA[wv][l][7] = q4.w;
    }
    __syncthreads();
    if (tid < 128) {
        const int which = tid >> 6, d = tid & 63;
        float v = 0.f;
        #pragma unroll
        for (int w = 0; w < 4; ++w) v += sA[w][d >> 2][which * 4 + (d & 3)];
        part[blockIdx.x * 128 + tid] = v;
    }
}

// ---------------------------------------------------------------------------
// k_inproj: h1 = selu(bn(att) @ inproj + b) via split-bf16 MFMA (R7).
// ---------------------------------------------------------------------------
__global__ __launch_bounds__(256) void k_inproj(
    const float* __restrict__ att, const float* __restrict__ partials1,
    const float* __restrict__ bn_g, const float* __restrict__ bn_b,
    const unsigned short* __restrict__ ipf_hi, const unsigned short* __restrict__ ipf_lo,
    const float* __restrict__ ip_b,
    float* __restrict__ h1, float* __restrict__ partials2)
{
    __shared__ float sSt[128], sTmp[128], sP[4][128];
    const int tid = threadIdx.x, wv = tid >> 6, l = tid & 63;
    const int h = l >> 4, c16 = l & 15;

    if (tid < 128) {
        float s = 0.f;
        for (int k = 0; k < 32; ++k) s += partials1[k * 128 + tid];
        sTmp[tid] = s;
    }
    __syncthreads();
    if (tid < 64) {
        const float m = sTmp[tid] * (1.0f / B_);
        const float var = fmaxf(sTmp[64 + tid] * (1.0f / B_) - m * m, 0.0f);
        const float istd = rsqrtf(var + 1e-5f);
        const float sc = istd * bn_g[tid];
        sSt[tid] = sc; sSt[64 + tid] = bn_b[tid] - m * sc;
    }
    __syncthreads();

    const int r0 = blockIdx.x * 64 + wv * 16;
    const int row = r0 + c16;
    const float4* xr = reinterpret_cast<const float4*>(att + (size_t)row * 64);
    const float4 x0 = xr[2 * h], x1 = xr[2 * h + 1], x2 = xr[8 + 2 * h], x3v = xr[9 + 2 * h];
    const float4* st4 = reinterpret_cast<const float4*>(sSt);
    const float4 sc0 = st4[2 * h], sc1 = st4[2 * h + 1], sh0 = st4[16 + 2 * h], sh1 = st4[17 + 2 * h];
    const float4 sc2 = st4[8 + 2 * h], sc3 = st4[9 + 2 * h], sh2 = st4[24 + 2 * h], sh3 = st4[25 + 2 * h];

    float xn0[8], xn1[8];
    #pragma unroll
    for (int q = 0; q < 4; ++q) {
        xn0[q]     = fmaf((&x0.x)[q], (&sc0.x)[q], (&sh0.x)[q]);
        xn0[4 + q] = fmaf((&x1.x)[q], (&sc1.x)[q], (&sh1.x)[q]);
        xn1[q]     = fmaf((&x2.x)[q], (&sc2.x)[q], (&sh2.x)[q]);
        xn1[4 + q] = fmaf((&x3v.x)[q], (&sc3.x)[q], (&sh3.x)[q]);
    }
    short8 ah0, al0, ah1, al1;
    #pragma unroll
    for (int j = 0; j < 8; ++j) {
        unsigned short hi, lo;
        split_(xn0[j], hi, lo); ah0[j] = (short)hi; al0[j] = (short)lo;
        split_(xn1[j], hi, lo); ah1[j] = (short)hi; al1[j] = (short)lo;
    }

    f32x4 acc[4];
    #pragma unroll
    for (int nb = 0; nb < 4; ++nb) acc[nb] = (f32x4){0.f, 0.f, 0.f, 0.f};
    #pragma unroll
    for (int s = 0; s < 2; ++s) {
        const short8 aH = s ? ah1 : ah0;
        const short8 aL = s ? al1 : al0;
        #pragma unroll
        for (int nb = 0; nb < 4; ++nb) {
            const short8 bh = reinterpret_cast<const short8*>(ipf_hi)[(s * 4 + nb) * 64 + l];
            const short8 bl = reinterpret_cast<const short8*>(ipf_lo)[(s * 4 + nb) * 64 + l];
            acc[nb] = __builtin_amdgcn_mfma_f32_16x16x32_bf16(aH, bh, acc[nb], 0, 0, 0);
            acc[nb] = __builtin_amdgcn_mfma_f32_16x16x32_bf16(aL, bh, acc[nb], 0, 0, 0);
            acc[nb] = __builtin_amdgcn_mfma_f32_16x16x32_bf16(aH, bl, acc[nb], 0, 0, 0);
        }
    }

    #pragma unroll
    for (int nb = 0; nb < 4; ++nb) {
        const int dim = 16 * nb + c16;
        const float bias = ip_b[dim];
        float sl = 0.f, sq = 0.f;
        #pragma unroll
        for (int r = 0; r < 4; ++r) {
            const float v = seluf_(acc[nb][r] + bias);
            h1[(size_t)(r0 + 4 * h + r) * 64 + dim] = v;
            sl += v; sq = fmaf(v, v, sq);
        }
        sl += __shfl_xor(sl, 16); sl += __shfl_xor(sl, 32);
        sq += __shfl_xor(sq, 16); sq += __shfl_xor(sq, 32);
        if (l < 16) { sP[wv][16 * nb + l] = sl; sP[wv][64 + 16 * nb + l] = sq; }
    }
    __syncthreads();
    if (tid < 128)
        partials2[blockIdx.x * 128 + tid] =
            sP[0][tid] + sP[1][tid] + sP[2][tid] + sP[3][tid];
}

// ---------------------------------------------------------------------------
// k_final: n = bn1(h1)@outproj+b (split-bf16); beta via gate1 (bf16);
// out = beta*self + (1-beta)*n. 64 blocks x 256 (R7).
// ---------------------------------------------------------------------------
__global__ __launch_bounds__(256) void k_final(
    const float* __restrict__ h1, const float* __restrict__ partials2,
    const float* __restrict__ bn1_g, const float* __restrict__ bn1_b,
    const unsigned short* __restrict__ opf_hi, const unsigned short* __restrict__ opf_lo,
    const float* __restrict__ op_b,
    const int* __restrict__ nodes, const float* __restrict__ u2e,
    const unsigned short* __restrict__ g1f, const float* __restrict__ g1_b,
    float* __restrict__ out)
{
    __shared__ float sSt[128], sTmp[128];
    __shared__ __align__(16) unsigned short sX3[4][16 * 200];
    const int tid = threadIdx.x, wv = tid >> 6, l = tid & 63;
    const int h = l >> 4, c16 = l & 15;

    if (tid < 128) {
        float s = 0.f;
        #pragma unroll 8
        for (int k = 0; k < 64; ++k) s += partials2[k * 128 + tid];
        sTmp[tid] = s;
    }
    __syncthreads();
    if (tid < 64) {
        const float m = sTmp[tid] * (1.0f / B_);
        const float var = fmaxf(sTmp[64 + tid] * (1.0f / B_) - m * m, 0.0f);
        const float istd = rsqrtf(var + 1e-5f);
        const float sc = istd * bn1_g[tid];
        sSt[tid] = sc; sSt[64 + tid] = bn1_b[tid] - m * sc;
    }
    __syncthreads();

    const int r0 = blockIdx.x * 64 + wv * 16;
    const int row = r0 + c16;
    const float4* xr = reinterpret_cast<const float4*>(h1 + (size_t)row * 64);
    const float4 x0 = xr[2 * h], x1 = xr[2 * h + 1], x2 = xr[8 + 2 * h], x3v = xr[9 + 2 * h];
    const float4* st4 = reinterpret_cast<const float4*>(sSt);
    const float4 sc0 = st4[2 * h], sc1 = st4[2 * h + 1], sh0 = st4[16 + 2 * h], sh1 = st4[17 + 2 * h];
    const float4 sc2 = st4[8 + 2 * h], sc3 = st4[9 + 2 * h], sh2 = st4[24 + 2 * h], sh3 = st4[25 + 2 * h];

    float xn0[8], xn1[8];
    #pragma unroll
    for (int q = 0; q < 4; ++q) {
        xn0[q]     = fmaf((&x0.x)[q], (&sc0.x)[q], (&sh0.x)[q]);
        xn0[4 + q] = fmaf((&x1.x)[q], (&sc1.x)[q], (&sh1.x)[q]);
        xn1[q]     = fmaf((&x2.x)[q], (&sc2.x)[q], (&sh2.x)[q]);
        xn1[4 + q] = fmaf((&x3v.x)[q], (&sc3.x)[q], (&sh3.x)[q]);
    }
    short8 ah0, al0, ah1, al1;
    #pragma unroll
    for (int j = 0; j < 8; ++j) {
        unsigned short hi, lo;
        split_(xn0[j], hi, lo); ah0[j] = (short)hi; al0[j] = (short)lo;
        split_(xn1[j], hi, lo); ah1[j] = (short)hi; al1[j] = (short)lo;
    }

    f32x4 acc[4];
    #pragma unroll
    for (int nb = 0; nb < 4; ++nb) acc[nb] = (f32x4){0.f, 0.f, 0.f, 0.f};
    #pragma unroll
    for (int s = 0; s < 2; ++s) {
        const short8 aH = s ? ah1 : ah0;
        const short8 aL = s ? al1 : al0;
        #pragma unroll
        for (int nb = 0; nb < 4; ++nb) {
            const short8 bh = reinterpret_cast<const short8*>(opf_hi)[(s * 4 + nb) * 64 + l];
            const short8 bl = reinterpret_cast<const short8*>(opf_lo)[(s * 4 + nb) * 64 + l];
            acc[nb] = __builtin_amdgcn_mfma_f32_16x16x32_bf16(aH, bh, acc[nb], 0, 0, 0);
            acc[nb] = __builtin_amdgcn_mfma_f32_16x16x32_bf16(aL, bh, acc[nb], 0, 0, 0);
            acc[nb] = __builtin_amdgcn_mfma_f32_16x16x32_bf16(aH, bl, acc[nb], 0, 0, 0);
        }
    }

    int nd[4];
    #pragma unroll
    for (int r = 0; r < 4; ++r) nd[r] = nodes[r0 + 4 * h + r];

    float nn[4][4], sf[4][4];
    unsigned short* X = sX3[wv];
    #pragma unroll
    for (int nb = 0; nb < 4; ++nb) {
        const int dim = 16 * nb + c16;
        const float bias = op_b[dim];
        #pragma unroll
        for (int r = 0; r < 4; ++r) {
            const float v = acc[nb][r] + bias;
            const float s = u2e[(size_t)nd[r] * 64 + dim];
            nn[nb][r] = v; sf[nb][r] = s;
            const int rI = 4 * h + r;
            X[rI * 200 + dim]       = bf16_(s);
            X[rI * 200 + 64 + dim]  = bf16_(v);
            X[rI * 200 + 128 + dim] = bf16_(s * v);
        }
    }
    __builtin_amdgcn_wave_barrier();
    __syncthreads();

    f32x4 acc3[4];
    #pragma unroll
    for (int nb = 0; nb < 4; ++nb) acc3[nb] = (f32x4){0.f, 0.f, 0.f, 0.f};
    #pragma unroll
    for (int s = 0; s < 6; ++s) {
        const short8 a3 = *reinterpret_cast<const short8*>(&sX3[wv][c16 * 200 + 32 * s + 8 * h]);
        #pragma unroll
        for (int nb = 0; nb < 4; ++nb)
            acc3[nb] = __builtin_amdgcn_mfma_f32_16x16x32_bf16(
                a3, reinterpret_cast<const short8*>(g1f)[(s * 4 + nb) * 64 + l], acc3[nb], 0, 0, 0);
    }

    #pragma unroll
    for (int nb = 0; nb < 4; ++nb) {
        const int dim = 16 * nb + c16;
        const float gb = g1_b[dim];
        #pragma unroll
        for (int r = 0; r < 4; ++r) {
            const float beta = sigfast_(acc3[nb][r] + gb);
            out[(size_t)(r0 + 4 * h + r) * 64 + dim] =
                beta * sf[nb][r] + (1.0f - beta) * nn[nb][r];
        }
    }
}

extern "C" void kernel_launch(void* const* d_in, const int* in_sizes, int n_in,
                              void* d_out, int out_size, void* d_ws, size_t ws_size,
                              hipStream_t stream) {
    (void)in_sizes; (void)n_in; (void)out_size; (void)ws_size;
    const int*   nodes     = (const int*)d_in[0];
    const int*   hist_ui   = (const int*)d_in[1];
    const int*   hist_r    = (const int*)d_in[2];
    const float* i2e_w     = (const float*)d_in[3];
    const float* u2e_w     = (const float*)d_in[4];
    const float* r2e_w     = (const float*)d_in[5];
    // d_in[6..13]: attention-score MLP params -- dead code (entmax over a
    // size-1 axis == 1.0 identically; head-1 renorm of unit vectors is identity).
    const float* gate_w    = (const float*)d_in[14];
    const float* gate_b    = (const float*)d_in[15];
    const float* gate1_w   = (const float*)d_in[16];
    const float* gate1_b   = (const float*)d_in[17];
    const float* bn_g      = (const float*)d_in[18];
    const float* bn_b      = (const float*)d_in[19];
    const float* inproj_w  = (const float*)d_in[20];
    const float* inproj_b  = (const float*)d_in[21];
    const float* bn1_g     = (const float*)d_in[22];
    const float* bn1_b     = (const float*)d_in[23];
    const float* outproj_w = (const float*)d_in[24];
    const float* outproj_b = (const float*)d_in[25];

    float* out = (float*)d_out;
    float* ws  = (float*)d_ws;
    // Float-offset workspace layout (non-overlapping; ~2.2 MB total):
    float* ws_att = ws;                              // [0, 262144)
    float* ws_h1  = ws + 262144;                     // [262144, 524288)
    float* cbuf   = ws + 524288;                     // [524288, 524672)
    unsigned short* wfrag  = (unsigned short*)(ws + 524672);  // 16 KB -> 528768
    unsigned short* ipf_hi = (unsigned short*)(ws + 528768);  // 8 KB  -> 530816
    unsigned short* ipf_lo = (unsigned short*)(ws + 530816);  // 8 KB  -> 532864
    unsigned short* opf_hi = (unsigned short*)(ws + 532864);  // 8 KB  -> 534912
    unsigned short* opf_lo = (unsigned short*)(ws + 534912);  // 8 KB  -> 536960
    unsigned short* g1f    = (unsigned short*)(ws + 536960);  // 24 KB -> 543104
    float* partials1 = ws + 543104;                  // 32*128  -> 547200
    float* partials2 = ws + 547200;                  // 64*128  -> 555392

    pk_all<<<8, 256, 0, stream>>>(gate_w, gate_b, r2e_w, inproj_w, outproj_w,
                                  gate1_w, wfrag, cbuf, ipf_hi, ipf_lo,
                                  opf_hi, opf_lo, g1f);
    k1_fuse<<<B_ / 2, 256, 0, stream>>>(hist_ui, hist_r, i2e_w, r2e_w,
                                        wfrag, cbuf, ws_att);
    k_statsP<<<32, 256, 0, stream>>>(ws_att, partials1);
    k_inproj<<<64, 256, 0, stream>>>(ws_att, partials1, bn_g, bn_b, ipf_hi, ipf_lo,
                                     inproj_b, ws_h1, partials2);
    k_final<<<64, 256, 0, stream>>>(ws_h1, partials2, bn1_g, bn1_b, opf_hi, opf_lo,
                                    outproj_b, nodes, u2e_w, g1f, gate1_b, out);
}